// Round 1
// baseline (445.844 us; speedup 1.0000x reference)
//
#include <hip/hip_runtime.h>
#include <hip/hip_bf16.h>
#include <cstdint>
#include <cstddef>

typedef __hip_bfloat16 bf16;
typedef __attribute__((ext_vector_type(8))) __bf16 bf16x8;
typedef __attribute__((ext_vector_type(4))) float floatx4;

#define GPTR(p) ((const __attribute__((address_space(1))) void*)(p))
#define LPTR(p) ((__attribute__((address_space(3))) void*)(p))

__device__ __forceinline__ floatx4 mfma16(bf16x8 a, bf16x8 b, floatx4 c) {
  return __builtin_amdgcn_mfma_f32_16x16x32_bf16(a, b, c, 0, 0, 0);
}

// ---------------------------------------------------------------------------
// fp32 -> bf16 bulk convert (x and weights pre-cast once; removes the 64x
// redundant per-block W conversion that made round-7 GEMMs VALU-bound)
// ---------------------------------------------------------------------------
__global__ __launch_bounds__(256) void cvt_bf16(const float* __restrict__ in,
                                                bf16* __restrict__ out, int n4) {
  for (int i = blockIdx.x * 256 + threadIdx.x; i < n4; i += gridDim.x * 256) {
    float4 v = ((const float4*)in)[i];
    alignas(8) bf16 t[4] = {__float2bfloat16(v.x), __float2bfloat16(v.y),
                            __float2bfloat16(v.z), __float2bfloat16(v.w)};
    *(uint64_t*)(out + (size_t)i * 4) = *(const uint64_t*)t;
  }
}

// ---------------------------------------------------------------------------
// Fused QKV projection: A[8192,1024](bf16) @ [Wq;Wk;Wv](bf16)^T.
// m97 structure: 128x128 tile, BK=32, both sides global_load_lds width=16.
// grid (12, 64): nb 0-7 -> q (scaled, [B,H,T,64]); 8-9 -> k [B,G,T,64];
// 10-11 -> vT [B,G,64,T] (packed 8B transposed stores).
// ---------------------------------------------------------------------------
__global__ __launch_bounds__(256) void gemm_qkv(
    const bf16* __restrict__ A, const bf16* __restrict__ Wq,
    const bf16* __restrict__ Wk, const bf16* __restrict__ Wv,
    bf16* __restrict__ qout, bf16* __restrict__ kout,
    bf16* __restrict__ vTout) {
  __shared__ alignas(16) bf16 As[128 * 32];
  __shared__ alignas(16) bf16 Bs[128 * 32];
  const int tid = threadIdx.x;
  const int lane = tid & 63;
  const int w = tid >> 6;
  const int wr = w >> 1, wc = w & 1;
  const int quad = lane >> 4, c = lane & 15;
  const int m0 = blockIdx.y * 128;
  const int nb = blockIdx.x;

  int mode, nloc;
  const bf16* Wp;
  if (nb < 8) {
    mode = 1; Wp = Wq + (size_t)nb * 128 * 1024; nloc = nb * 128;
  } else if (nb < 10) {
    mode = 2; Wp = Wk + (size_t)(nb - 8) * 128 * 1024; nloc = (nb - 8) * 128;
  } else {
    mode = 3; Wp = Wv + (size_t)(nb - 10) * 128 * 1024; nloc = (nb - 10) * 128;
  }

  const int i0 = tid, i1 = tid + 256;
  const bf16* ga0 = A + (size_t)(m0 + (i0 >> 2)) * 1024 + (i0 & 3) * 8;
  const bf16* ga1 = A + (size_t)(m0 + (i1 >> 2)) * 1024 + (i1 & 3) * 8;
  const bf16* gb0 = Wp + (size_t)(i0 >> 2) * 1024 + (i0 & 3) * 8;
  const bf16* gb1 = Wp + (size_t)(i1 >> 2) * 1024 + (i1 & 3) * 8;

  floatx4 acc[4][4] = {};

  for (int kt = 0; kt < 32; ++kt) {
    if (kt) __syncthreads();
    __builtin_amdgcn_global_load_lds(GPTR(ga0), LPTR(&As[i0 * 8]), 16, 0, 0);
    __builtin_amdgcn_global_load_lds(GPTR(ga1), LPTR(&As[i1 * 8]), 16, 0, 0);
    __builtin_amdgcn_global_load_lds(GPTR(gb0), LPTR(&Bs[i0 * 8]), 16, 0, 0);
    __builtin_amdgcn_global_load_lds(GPTR(gb1), LPTR(&Bs[i1 * 8]), 16, 0, 0);
    ga0 += 32; ga1 += 32; gb0 += 32; gb1 += 32;
    __syncthreads();
    bf16x8 af[4], bfr[4];
#pragma unroll
    for (int i = 0; i < 4; ++i)
      af[i] = *(const bf16x8*)&As[(wr * 64 + i * 16 + c) * 32 + quad * 8];
#pragma unroll
    for (int j = 0; j < 4; ++j)
      bfr[j] = *(const bf16x8*)&Bs[(wc * 64 + j * 16 + c) * 32 + quad * 8];
#pragma unroll
    for (int i = 0; i < 4; ++i)
#pragma unroll
      for (int j = 0; j < 4; ++j)
        acc[i][j] = mfma16(af[i], bfr[j], acc[i][j]);
  }

  if (mode == 3) {  // vT[((b*4+g)*64+d)*1024+t]: 4 consecutive t -> 8B store
#pragma unroll
    for (int i = 0; i < 4; ++i)
#pragma unroll
      for (int j = 0; j < 4; ++j) {
        int m = m0 + wr * 64 + i * 16 + quad * 4;
        int n = nloc + wc * 64 + j * 16 + c;
        int b = m >> 10, t = m & 1023, g = n >> 6, d = n & 63;
        alignas(8) bf16 tmp[4];
#pragma unroll
        for (int r = 0; r < 4; ++r) tmp[r] = __float2bfloat16(acc[i][j][r]);
        *(uint64_t*)(vTout + (((size_t)(b * 4 + g)) * 64 + d) * 1024 + t) =
            *(const uint64_t*)tmp;
      }
    return;
  }

  const float scale = (mode == 1) ? 0.125f : 1.0f;
#pragma unroll
  for (int i = 0; i < 4; ++i)
#pragma unroll
    for (int j = 0; j < 4; ++j)
#pragma unroll
      for (int r = 0; r < 4; ++r) {
        int m = m0 + wr * 64 + i * 16 + quad * 4 + r;
        int n = nloc + wc * 64 + j * 16 + c;
        int b = m >> 10, t = m & 1023;
        bf16 v = __float2bfloat16(acc[i][j][r] * scale);
        if (mode == 1) {
          int h = n >> 6;
          qout[(((size_t)(b * 16 + h)) * 1024 + t) * 64 + (n & 63)] = v;
        } else {
          int g = n >> 6;
          kout[(((size_t)(b * 4 + g)) * 1024 + t) * 64 + (n & 63)] = v;
        }
      }
}

// ---------------------------------------------------------------------------
// O-projection: attn[8192,1024](bf16) @ Wo(bf16)^T -> fp32 d_out.
// Same m97 dual global_load_lds staging.
// ---------------------------------------------------------------------------
__global__ __launch_bounds__(256) void gemm_o(const bf16* __restrict__ A,
                                              const bf16* __restrict__ W,
                                              float* __restrict__ out) {
  __shared__ alignas(16) bf16 As[128 * 32];
  __shared__ alignas(16) bf16 Bs[128 * 32];
  const int tid = threadIdx.x;
  const int lane = tid & 63;
  const int w = tid >> 6;
  const int wr = w >> 1, wc = w & 1;
  const int quad = lane >> 4, c = lane & 15;
  const int m0 = blockIdx.y * 128, n0 = blockIdx.x * 128;

  const int i0 = tid, i1 = tid + 256;
  const bf16* ga0 = A + (size_t)(m0 + (i0 >> 2)) * 1024 + (i0 & 3) * 8;
  const bf16* ga1 = A + (size_t)(m0 + (i1 >> 2)) * 1024 + (i1 & 3) * 8;
  const bf16* gb0 = W + (size_t)(n0 + (i0 >> 2)) * 1024 + (i0 & 3) * 8;
  const bf16* gb1 = W + (size_t)(n0 + (i1 >> 2)) * 1024 + (i1 & 3) * 8;

  floatx4 acc[4][4] = {};

  for (int kt = 0; kt < 32; ++kt) {
    if (kt) __syncthreads();
    __builtin_amdgcn_global_load_lds(GPTR(ga0), LPTR(&As[i0 * 8]), 16, 0, 0);
    __builtin_amdgcn_global_load_lds(GPTR(ga1), LPTR(&As[i1 * 8]), 16, 0, 0);
    __builtin_amdgcn_global_load_lds(GPTR(gb0), LPTR(&Bs[i0 * 8]), 16, 0, 0);
    __builtin_amdgcn_global_load_lds(GPTR(gb1), LPTR(&Bs[i1 * 8]), 16, 0, 0);
    ga0 += 32; ga1 += 32; gb0 += 32; gb1 += 32;
    __syncthreads();
    bf16x8 af[4], bfr[4];
#pragma unroll
    for (int i = 0; i < 4; ++i)
      af[i] = *(const bf16x8*)&As[(wr * 64 + i * 16 + c) * 32 + quad * 8];
#pragma unroll
    for (int j = 0; j < 4; ++j)
      bfr[j] = *(const bf16x8*)&Bs[(wc * 64 + j * 16 + c) * 32 + quad * 8];
#pragma unroll
    for (int i = 0; i < 4; ++i)
#pragma unroll
      for (int j = 0; j < 4; ++j)
        acc[i][j] = mfma16(af[i], bfr[j], acc[i][j]);
  }

#pragma unroll
  for (int i = 0; i < 4; ++i)
#pragma unroll
    for (int j = 0; j < 4; ++j)
#pragma unroll
      for (int r = 0; r < 4; ++r) {
        int m = m0 + wr * 64 + i * 16 + quad * 4 + r;
        int n = n0 + wc * 64 + j * 16 + c;
        out[(size_t)m * 1024 + n] = acc[i][j][r];
      }
}

// ---------------------------------------------------------------------------
// Flash attention, S^T = K.Q^T form.
// Round-8 restructure: K/V per (b,g) are 128 KB each and shared by 64 blocks
// -> L2-resident. Old version staged them to LDS with 2-3 __syncthreads()/tile
// and no double-buffer: MfmaUtil 11.5% + VALUBusy 37.6% = half the time ALL
// pipes idle (barrier-drain latency). New version reads K/V MFMA fragments
// DIRECTLY from global (L1/L2 serve; 4 waves/block read identical frags).
// P gets its own LDS buffer (was aliased onto Ks) -> ZERO block barriers in
// the main loop; waves slip freely, TLP hides L2 latency.
// LDS: qEl 33792 + P 9216 = 43008 B -> 3 blocks/CU (unchanged).
// ---------------------------------------------------------------------------
__global__ __launch_bounds__(256, 3) void attn_kernel(
    const bf16* __restrict__ q_ws, const bf16* __restrict__ k_ws,
    const bf16* __restrict__ vT, const float* __restrict__ E,
    bf16* __restrict__ out) {
  __shared__ alignas(16) bf16 qEl[64 * 264];  // bias table, rows lane-private
  __shared__ alignas(16) bf16 Ps[64 * 72];    // P rows (wave-private)
  const int tid = threadIdx.x;
  const int lane = tid & 63, w = tid >> 6;
  const int quad = lane >> 4, c = lane & 15;
  const int bh = blockIdx.y;
  const int b = bh >> 4, h = bh & 15, g = h >> 2;
  const int qb = blockIdx.x * 64 + w * 16;

  const bf16* qrow = q_ws + ((size_t)bh * 1024 + qb + c) * 64;
  bf16x8 qf0 = *(const bf16x8*)(qrow + quad * 8);
  bf16x8 qf1 = *(const bf16x8*)(qrow + 32 + quad * 8);

  // qE[qlocal][p] = q.E[p]  (wave's rows w*16..w*16+15; p in [0,254])
  for (int jn = 0; jn < 16; ++jn) {
    int er = jn * 16 + c;
    er = er > 254 ? 254 : er;
    const float* Ep = E + (size_t)er * 64;
    float4 e0 = *(const float4*)(Ep + quad * 8);
    float4 e1 = *(const float4*)(Ep + quad * 8 + 4);
    float4 e2 = *(const float4*)(Ep + 32 + quad * 8);
    float4 e3 = *(const float4*)(Ep + 32 + quad * 8 + 4);
    alignas(16) bf16 t0b[8] = {
        __float2bfloat16(e0.x), __float2bfloat16(e0.y), __float2bfloat16(e0.z),
        __float2bfloat16(e0.w), __float2bfloat16(e1.x), __float2bfloat16(e1.y),
        __float2bfloat16(e1.z), __float2bfloat16(e1.w)};
    alignas(16) bf16 t1b[8] = {
        __float2bfloat16(e2.x), __float2bfloat16(e2.y), __float2bfloat16(e2.z),
        __float2bfloat16(e2.w), __float2bfloat16(e3.x), __float2bfloat16(e3.y),
        __float2bfloat16(e3.z), __float2bfloat16(e3.w)};
    floatx4 a = {};
    a = mfma16(qf0, *(const bf16x8*)t0b, a);
    a = mfma16(qf1, *(const bf16x8*)t1b, a);
#pragma unroll
    for (int r = 0; r < 4; ++r)
      qEl[(w * 16 + quad * 4 + r) * 264 + jn * 16 + c] = __float2bfloat16(a[r]);
  }
  __syncthreads();  // only block barrier in the kernel: qEl ready

  const bf16* rowE = qEl + (size_t)(w * 16 + c) * 264;
  bf16* rowP = Ps + (size_t)(w * 16 + c) * 72;
  float mrow = -1e30f, lrow = 0.f;
  floatx4 o[4] = {};
  const bf16* kbase = k_ws + (size_t)(b * 4 + g) * 1024 * 64;
  const bf16* vbase = vT + (size_t)(b * 4 + g) * 64 * 1024;
  const float blo = __bfloat162float(rowE[254]);
  const float bhi = __bfloat162float(rowE[0]);

  for (int t0 = 0; t0 < 1024; t0 += 64) {
    // --- K fragments: direct from global (L2-resident; frag addrs are
    // wave-invariant so 4 waves/block hit L1). 8 independent 16B loads.
    bf16x8 kf[4][2];
#pragma unroll
    for (int j = 0; j < 4; ++j) {
      const bf16* kr = kbase + (size_t)(t0 + j * 16 + c) * 64 + quad * 8;
      kf[j][0] = *(const bf16x8*)kr;
      kf[j][1] = *(const bf16x8*)(kr + 32);
    }
    floatx4 S[4];
#pragma unroll
    for (int j = 0; j < 4; ++j) {
      floatx4 z = {};
      z = mfma16(kf[j][0], qf0, z);
      S[j] = mfma16(kf[j][1], qf1, z);
    }
    // --- V fragments: issue now so L2 latency hides under softmax VALU work.
    bf16x8 vf[4][2];
#pragma unroll
    for (int jj = 0; jj < 4; ++jj) {
      const bf16* vr = vbase + (size_t)(jj * 16 + c) * 1024 + t0 + quad * 8;
      vf[jj][0] = *(const bf16x8*)vr;
      vf[jj][1] = *(const bf16x8*)(vr + 32);
    }
    // --- relative-position bias
    const int dlt0 = qb + c - t0;
    if (t0 <= qb - 190) {
#pragma unroll
      for (int j = 0; j < 4; ++j)
#pragma unroll
        for (int r = 0; r < 4; ++r) S[j][r] += blo;
    } else if (t0 >= qb + 142) {
#pragma unroll
      for (int j = 0; j < 4; ++j)
#pragma unroll
        for (int r = 0; r < 4; ++r) S[j][r] += bhi;
    } else {
#pragma unroll
      for (int j = 0; j < 4; ++j)
#pragma unroll
        for (int r = 0; r < 4; ++r) {
          int dlt = dlt0 - j * 16 - quad * 4 - r;
          dlt = dlt > 127 ? 127 : (dlt < -127 ? -127 : dlt);
          S[j][r] += __bfloat162float(rowE[dlt + 127]);
        }
    }
    // --- online softmax
    float mx = -1e30f;
#pragma unroll
    for (int j = 0; j < 4; ++j)
#pragma unroll
      for (int r = 0; r < 4; ++r) mx = fmaxf(mx, S[j][r]);
    mx = fmaxf(mx, __shfl_xor(mx, 16, 64));
    mx = fmaxf(mx, __shfl_xor(mx, 32, 64));
    float nm = fmaxf(mrow, mx);
    float alpha = __expf(mrow - nm);
    float rs = 0.f;
#pragma unroll
    for (int j = 0; j < 4; ++j)
#pragma unroll
      for (int r = 0; r < 4; ++r) {
        float p = __expf(S[j][r] - nm);
        S[j][r] = p;
        rs += p;
      }
    rs += __shfl_xor(rs, 16, 64);
    rs += __shfl_xor(rs, 32, 64);
    lrow = lrow * alpha + rs;
    mrow = nm;
    // --- P through wave-private LDS rows (wave-level sync only)
#pragma unroll
    for (int j = 0; j < 4; ++j) {
      alignas(8) bf16 tmp[4];
#pragma unroll
      for (int r = 0; r < 4; ++r) tmp[r] = __float2bfloat16(S[j][r]);
      *(uint64_t*)(rowP + j * 16 + quad * 4) = *(const uint64_t*)tmp;
    }
    float av[4];
#pragma unroll
    for (int r = 0; r < 4; ++r) av[r] = __shfl(alpha, quad * 4 + r, 64);
#pragma unroll
    for (int jj = 0; jj < 4; ++jj)
#pragma unroll
      for (int r = 0; r < 4; ++r) o[jj][r] *= av[r];
    __threadfence_block();
    __builtin_amdgcn_wave_barrier();
    bf16x8 pf0 = *(const bf16x8*)(rowP + quad * 8);
    bf16x8 pf1 = *(const bf16x8*)(rowP + 32 + quad * 8);
#pragma unroll
    for (int jj = 0; jj < 4; ++jj) {
      o[jj] = mfma16(pf0, vf[jj][0], o[jj]);
      o[jj] = mfma16(pf1, vf[jj][1], o[jj]);
    }
  }

  float lr4[4];
#pragma unroll
  for (int r = 0; r < 4; ++r) lr4[r] = __shfl(lrow, quad * 4 + r, 64);
#pragma unroll
  for (int jj = 0; jj < 4; ++jj)
#pragma unroll
    for (int r = 0; r < 4; ++r) {
      int qi = qb + quad * 4 + r;
      out[(((size_t)b * 1024 + qi) * 16 + h) * 64 + jj * 16 + c] =
          __float2bfloat16(o[jj][r] / lr4[r]);
    }
}

// ---------------------------------------------------------------------------
// Memory plan (ws stays at the PROVEN 24 MB; weights overlap dead regions):
//   d_out (32 MB fp32): [0,16M) q bf16 | [16M,32M) x_bf16 (both dead before
//     gemm_o overwrites d_out).
//   ws: k 4MB @0 | vT 4MB @4M | attn 16MB @8M
//   Wq/Wk/Wv_bf @8M/10M/10.5M  (inside attn region; dead before attn_kernel
//     writes it — stream-ordered).
//   Wo_bf @0 (inside k region; converted AFTER attn_kernel consumed k).
// ---------------------------------------------------------------------------
extern "C" void kernel_launch(void* const* d_in, const int* in_sizes, int n_in,
                              void* d_out, int out_size, void* d_ws,
                              size_t ws_size, hipStream_t stream) {
  const float* x = (const float*)d_in[0];
  const float* Wq = (const float*)d_in[1];
  const float* Wk = (const float*)d_in[2];
  const float* Wv = (const float*)d_in[3];
  const float* Wo = (const float*)d_in[4];
  const float* E = (const float*)d_in[5];

  char* ws = (char*)d_ws;
  bf16* q_ws = (bf16*)d_out;                           // [0,16M) of d_out
  bf16* x_bf = (bf16*)((char*)d_out + (16ull << 20));  // [16M,32M) of d_out
  bf16* k_ws = (bf16*)(ws);
  bf16* vT = (bf16*)(ws + (4ull << 20));
  bf16* attn = (bf16*)(ws + (8ull << 20));
  bf16* Wq_bf = (bf16*)(ws + (8ull << 20));            // 2 MB   (attn region)
  bf16* Wk_bf = (bf16*)(ws + (10ull << 20));           // 0.5 MB (attn region)
  bf16* Wv_bf = (bf16*)(ws + (10ull << 20) + (512ull << 10));  // 0.5 MB
  bf16* Wo_bf = (bf16*)(ws);                           // 2 MB   (k region)
  float* outp = (float*)d_out;

  cvt_bf16<<<2048, 256, 0, stream>>>(x, x_bf, 2097152);
  cvt_bf16<<<1024, 256, 0, stream>>>(Wq, Wq_bf, 262144);
  cvt_bf16<<<256, 256, 0, stream>>>(Wk, Wk_bf, 65536);
  cvt_bf16<<<256, 256, 0, stream>>>(Wv, Wv_bf, 65536);
  gemm_qkv<<<dim3(12, 64), 256, 0, stream>>>(x_bf, Wq_bf, Wk_bf, Wv_bf,
                                             q_ws, k_ws, vT);
  attn_kernel<<<dim3(16, 128), 256, 0, stream>>>(q_ws, k_ws, vT, E, attn);
  cvt_bf16<<<1024, 256, 0, stream>>>(Wo, Wo_bf, 262144);
  gemm_o<<<dim3(8, 64), 256, 0, stream>>>(attn, Wo_bf, outp);
}

// Round 2
// 394.069 us; speedup vs baseline: 1.1314x; 1.1314x over previous
//
#include <hip/hip_runtime.h>
#include <hip/hip_bf16.h>
#include <cstdint>
#include <cstddef>

typedef __hip_bfloat16 bf16;
typedef __attribute__((ext_vector_type(8))) __bf16 bf16x8;
typedef __attribute__((ext_vector_type(4))) float floatx4;

#define GPTR(p) ((const __attribute__((address_space(1))) void*)(p))
#define LPTR(p) ((__attribute__((address_space(3))) void*)(p))

__device__ __forceinline__ floatx4 mfma16(bf16x8 a, bf16x8 b, floatx4 c) {
  return __builtin_amdgcn_mfma_f32_16x16x32_bf16(a, b, c, 0, 0, 0);
}

// ---------------------------------------------------------------------------
// fp32 -> bf16 bulk convert (x and weights pre-cast once; removes the 64x
// redundant per-block W conversion that made round-7 GEMMs VALU-bound)
// ---------------------------------------------------------------------------
__global__ __launch_bounds__(256) void cvt_bf16(const float* __restrict__ in,
                                                bf16* __restrict__ out, int n4) {
  for (int i = blockIdx.x * 256 + threadIdx.x; i < n4; i += gridDim.x * 256) {
    float4 v = ((const float4*)in)[i];
    alignas(8) bf16 t[4] = {__float2bfloat16(v.x), __float2bfloat16(v.y),
                            __float2bfloat16(v.z), __float2bfloat16(v.w)};
    *(uint64_t*)(out + (size_t)i * 4) = *(const uint64_t*)t;
  }
}

// ---------------------------------------------------------------------------
// Fused QKV projection: A[8192,1024](bf16) @ [Wq;Wk;Wv](bf16)^T.
// m97 structure: 128x128 tile, BK=32, both sides global_load_lds width=16.
// grid (12, 64): nb 0-7 -> q (scaled, [B,H,T,64]); 8-9 -> k [B,G,T,64];
// 10-11 -> vT [B,G,64,T] (packed 8B transposed stores).
// ---------------------------------------------------------------------------
__global__ __launch_bounds__(256) void gemm_qkv(
    const bf16* __restrict__ A, const bf16* __restrict__ Wq,
    const bf16* __restrict__ Wk, const bf16* __restrict__ Wv,
    bf16* __restrict__ qout, bf16* __restrict__ kout,
    bf16* __restrict__ vTout) {
  __shared__ alignas(16) bf16 As[128 * 32];
  __shared__ alignas(16) bf16 Bs[128 * 32];
  const int tid = threadIdx.x;
  const int lane = tid & 63;
  const int w = tid >> 6;
  const int wr = w >> 1, wc = w & 1;
  const int quad = lane >> 4, c = lane & 15;
  const int m0 = blockIdx.y * 128;
  const int nb = blockIdx.x;

  int mode, nloc;
  const bf16* Wp;
  if (nb < 8) {
    mode = 1; Wp = Wq + (size_t)nb * 128 * 1024; nloc = nb * 128;
  } else if (nb < 10) {
    mode = 2; Wp = Wk + (size_t)(nb - 8) * 128 * 1024; nloc = (nb - 8) * 128;
  } else {
    mode = 3; Wp = Wv + (size_t)(nb - 10) * 128 * 1024; nloc = (nb - 10) * 128;
  }

  const int i0 = tid, i1 = tid + 256;
  const bf16* ga0 = A + (size_t)(m0 + (i0 >> 2)) * 1024 + (i0 & 3) * 8;
  const bf16* ga1 = A + (size_t)(m0 + (i1 >> 2)) * 1024 + (i1 & 3) * 8;
  const bf16* gb0 = Wp + (size_t)(i0 >> 2) * 1024 + (i0 & 3) * 8;
  const bf16* gb1 = Wp + (size_t)(i1 >> 2) * 1024 + (i1 & 3) * 8;

  floatx4 acc[4][4] = {};

  for (int kt = 0; kt < 32; ++kt) {
    if (kt) __syncthreads();
    __builtin_amdgcn_global_load_lds(GPTR(ga0), LPTR(&As[i0 * 8]), 16, 0, 0);
    __builtin_amdgcn_global_load_lds(GPTR(ga1), LPTR(&As[i1 * 8]), 16, 0, 0);
    __builtin_amdgcn_global_load_lds(GPTR(gb0), LPTR(&Bs[i0 * 8]), 16, 0, 0);
    __builtin_amdgcn_global_load_lds(GPTR(gb1), LPTR(&Bs[i1 * 8]), 16, 0, 0);
    ga0 += 32; ga1 += 32; gb0 += 32; gb1 += 32;
    __syncthreads();
    bf16x8 af[4], bfr[4];
#pragma unroll
    for (int i = 0; i < 4; ++i)
      af[i] = *(const bf16x8*)&As[(wr * 64 + i * 16 + c) * 32 + quad * 8];
#pragma unroll
    for (int j = 0; j < 4; ++j)
      bfr[j] = *(const bf16x8*)&Bs[(wc * 64 + j * 16 + c) * 32 + quad * 8];
#pragma unroll
    for (int i = 0; i < 4; ++i)
#pragma unroll
      for (int j = 0; j < 4; ++j)
        acc[i][j] = mfma16(af[i], bfr[j], acc[i][j]);
  }

  if (mode == 3) {  // vT[((b*4+g)*64+d)*1024+t]: 4 consecutive t -> 8B store
#pragma unroll
    for (int i = 0; i < 4; ++i)
#pragma unroll
      for (int j = 0; j < 4; ++j) {
        int m = m0 + wr * 64 + i * 16 + quad * 4;
        int n = nloc + wc * 64 + j * 16 + c;
        int b = m >> 10, t = m & 1023, g = n >> 6, d = n & 63;
        alignas(8) bf16 tmp[4];
#pragma unroll
        for (int r = 0; r < 4; ++r) tmp[r] = __float2bfloat16(acc[i][j][r]);
        *(uint64_t*)(vTout + (((size_t)(b * 4 + g)) * 64 + d) * 1024 + t) =
            *(const uint64_t*)tmp;
      }
    return;
  }

  const float scale = (mode == 1) ? 0.125f : 1.0f;
#pragma unroll
  for (int i = 0; i < 4; ++i)
#pragma unroll
    for (int j = 0; j < 4; ++j)
#pragma unroll
      for (int r = 0; r < 4; ++r) {
        int m = m0 + wr * 64 + i * 16 + quad * 4 + r;
        int n = nloc + wc * 64 + j * 16 + c;
        int b = m >> 10, t = m & 1023;
        bf16 v = __float2bfloat16(acc[i][j][r] * scale);
        if (mode == 1) {
          int h = n >> 6;
          qout[(((size_t)(b * 16 + h)) * 1024 + t) * 64 + (n & 63)] = v;
        } else {
          int g = n >> 6;
          kout[(((size_t)(b * 4 + g)) * 1024 + t) * 64 + (n & 63)] = v;
        }
      }
}

// ---------------------------------------------------------------------------
// O-projection: attn[8192,1024](bf16) @ Wo(bf16)^T -> fp32 d_out.
// Same m97 dual global_load_lds staging.
// ---------------------------------------------------------------------------
__global__ __launch_bounds__(256) void gemm_o(const bf16* __restrict__ A,
                                              const bf16* __restrict__ W,
                                              float* __restrict__ out) {
  __shared__ alignas(16) bf16 As[128 * 32];
  __shared__ alignas(16) bf16 Bs[128 * 32];
  const int tid = threadIdx.x;
  const int lane = tid & 63;
  const int w = tid >> 6;
  const int wr = w >> 1, wc = w & 1;
  const int quad = lane >> 4, c = lane & 15;
  const int m0 = blockIdx.y * 128, n0 = blockIdx.x * 128;

  const int i0 = tid, i1 = tid + 256;
  const bf16* ga0 = A + (size_t)(m0 + (i0 >> 2)) * 1024 + (i0 & 3) * 8;
  const bf16* ga1 = A + (size_t)(m0 + (i1 >> 2)) * 1024 + (i1 & 3) * 8;
  const bf16* gb0 = W + (size_t)(n0 + (i0 >> 2)) * 1024 + (i0 & 3) * 8;
  const bf16* gb1 = W + (size_t)(n0 + (i1 >> 2)) * 1024 + (i1 & 3) * 8;

  floatx4 acc[4][4] = {};

  for (int kt = 0; kt < 32; ++kt) {
    if (kt) __syncthreads();
    __builtin_amdgcn_global_load_lds(GPTR(ga0), LPTR(&As[i0 * 8]), 16, 0, 0);
    __builtin_amdgcn_global_load_lds(GPTR(ga1), LPTR(&As[i1 * 8]), 16, 0, 0);
    __builtin_amdgcn_global_load_lds(GPTR(gb0), LPTR(&Bs[i0 * 8]), 16, 0, 0);
    __builtin_amdgcn_global_load_lds(GPTR(gb1), LPTR(&Bs[i1 * 8]), 16, 0, 0);
    ga0 += 32; ga1 += 32; gb0 += 32; gb1 += 32;
    __syncthreads();
    bf16x8 af[4], bfr[4];
#pragma unroll
    for (int i = 0; i < 4; ++i)
      af[i] = *(const bf16x8*)&As[(wr * 64 + i * 16 + c) * 32 + quad * 8];
#pragma unroll
    for (int j = 0; j < 4; ++j)
      bfr[j] = *(const bf16x8*)&Bs[(wc * 64 + j * 16 + c) * 32 + quad * 8];
#pragma unroll
    for (int i = 0; i < 4; ++i)
#pragma unroll
      for (int j = 0; j < 4; ++j)
        acc[i][j] = mfma16(af[i], bfr[j], acc[i][j]);
  }

#pragma unroll
  for (int i = 0; i < 4; ++i)
#pragma unroll
    for (int j = 0; j < 4; ++j)
#pragma unroll
      for (int r = 0; r < 4; ++r) {
        int m = m0 + wr * 64 + i * 16 + quad * 4 + r;
        int n = n0 + wc * 64 + j * 16 + c;
        out[(size_t)m * 1024 + n] = acc[i][j][r];
      }
}

// ---------------------------------------------------------------------------
// Staged 64x64 bf16 tile with XOR-8 column-block swizzle (round-7, verified).
// ---------------------------------------------------------------------------
__device__ __forceinline__ void stage_tile_swz(const bf16* __restrict__ g,
                                               int gstride, bf16* __restrict__ dst,
                                               int tid) {
#pragma unroll
  for (int s = 0; s < 2; ++s) {
    int f = s * 256 + tid;
    int r = f >> 3, cb = f & 7;
    int cbg = cb ^ (r & 7);
    __builtin_amdgcn_global_load_lds(GPTR(g + (size_t)r * gstride + cbg * 8),
                                     LPTR(dst + f * 8), 16, 0, 0);
  }
}

__device__ __forceinline__ bf16x8 read_frag_swz(const bf16* __restrict__ tile,
                                                int row, int cb) {
  return *(const bf16x8*)&tile[row * 64 + ((cb ^ (row & 7)) * 8)];
}

// ---------------------------------------------------------------------------
// Flash attention, S^T = K.Q^T form.
// Round-2 pipeline (post-mortem of r1: direct K/V-from-global collapsed
// because the allocator rematerialized loads at use sites, VGPR stayed 68,
// full L2 latency exposed serially per wave).  This version:
//   - K: double-buffered LDS staging; prefetch tile t+1 at top of iter t;
//     ONE s_waitcnt vmcnt(0) at END of iter (prefetch had whole compute
//     phase to fly) + raw s_barrier -> no compiler drain at phase start.
//   - V: direct global->reg, pinned live via asm right after issue; issued
//     BEFORE the K prefetch so auto-wait before PV is vmcnt(2) (K prefetch
//     stays in flight).  +32 VGPR, still 3 blocks/CU.
//   - P aliases Kb[cur] (stride-72 rows) after mid-barrier, as round 0.
// LDS: qEl 33792 + 2*9216 = 52224 -> 3 blocks/CU.
// ---------------------------------------------------------------------------
__global__ __launch_bounds__(256, 3) void attn_kernel(
    const bf16* __restrict__ q_ws, const bf16* __restrict__ k_ws,
    const bf16* __restrict__ vT, const float* __restrict__ E,
    bf16* __restrict__ out) {
  __shared__ alignas(16) bf16 qEl[64 * 264];   // bias table, rows lane-private
  __shared__ alignas(16) bf16 Kb[2][64 * 72];  // K tile (linear 64x64) / P (stride 72)
  const int tid = threadIdx.x;
  const int lane = tid & 63, w = tid >> 6;
  const int quad = lane >> 4, c = lane & 15;
  const int bh = blockIdx.y;
  const int b = bh >> 4, h = bh & 15, g = h >> 2;
  const int qb = blockIdx.x * 64 + w * 16;

  const bf16* kbase = k_ws + (size_t)(b * 4 + g) * 1024 * 64;
  const bf16* vbase = vT + (size_t)(b * 4 + g) * 64 * 1024;

  // K tile 0 prefetch hides under the qE preamble; the preamble's
  // __syncthreads() drains it (vmcnt(0)) and makes it visible.
  stage_tile_swz(kbase, 64, Kb[0], tid);

  const bf16* qrow = q_ws + ((size_t)bh * 1024 + qb + c) * 64;
  bf16x8 qf0 = *(const bf16x8*)(qrow + quad * 8);
  bf16x8 qf1 = *(const bf16x8*)(qrow + 32 + quad * 8);

  // qE[qlocal][p] = q.E[p]  (wave's rows w*16..w*16+15; p in [0,254])
  for (int jn = 0; jn < 16; ++jn) {
    int er = jn * 16 + c;
    er = er > 254 ? 254 : er;
    const float* Ep = E + (size_t)er * 64;
    float4 e0 = *(const float4*)(Ep + quad * 8);
    float4 e1 = *(const float4*)(Ep + quad * 8 + 4);
    float4 e2 = *(const float4*)(Ep + 32 + quad * 8);
    float4 e3 = *(const float4*)(Ep + 32 + quad * 8 + 4);
    alignas(16) bf16 t0b[8] = {
        __float2bfloat16(e0.x), __float2bfloat16(e0.y), __float2bfloat16(e0.z),
        __float2bfloat16(e0.w), __float2bfloat16(e1.x), __float2bfloat16(e1.y),
        __float2bfloat16(e1.z), __float2bfloat16(e1.w)};
    alignas(16) bf16 t1b[8] = {
        __float2bfloat16(e2.x), __float2bfloat16(e2.y), __float2bfloat16(e2.z),
        __float2bfloat16(e2.w), __float2bfloat16(e3.x), __float2bfloat16(e3.y),
        __float2bfloat16(e3.z), __float2bfloat16(e3.w)};
    floatx4 a = {};
    a = mfma16(qf0, *(const bf16x8*)t0b, a);
    a = mfma16(qf1, *(const bf16x8*)t1b, a);
#pragma unroll
    for (int r = 0; r < 4; ++r)
      qEl[(w * 16 + quad * 4 + r) * 264 + jn * 16 + c] = __float2bfloat16(a[r]);
  }
  __syncthreads();  // qEl ready + K0 landed (full drain, once)

  const bf16* rowE = qEl + (size_t)(w * 16 + c) * 264;
  float mrow = -1e30f, lrow = 0.f;
  floatx4 o[4] = {};
  const float blo = __bfloat162float(rowE[254]);
  const float bhi = __bfloat162float(rowE[0]);

  for (int t = 0; t < 16; ++t) {
    const int t0 = t * 64;
    const int cur = t & 1;
    // --- V for THIS tile: direct global->reg, pinned live at iter top so
    // its L2 latency hides under QK + softmax.  Issued before K prefetch
    // so the auto-wait before PV is vmcnt(2), not vmcnt(0).
    bf16x8 vf[4][2];
#pragma unroll
    for (int jj = 0; jj < 4; ++jj) {
      const bf16* vr = vbase + (size_t)(jj * 16 + c) * 1024 + t0 + quad * 8;
      vf[jj][0] = *(const bf16x8*)vr;
      vf[jj][1] = *(const bf16x8*)(vr + 32);
    }
    asm volatile("" : "+v"(vf[0][0]), "+v"(vf[0][1]), "+v"(vf[1][0]),
                      "+v"(vf[1][1]), "+v"(vf[2][0]), "+v"(vf[2][1]),
                      "+v"(vf[3][0]), "+v"(vf[3][1]));
    // --- prefetch NEXT K tile into the other buffer (drained at iter end)
    stage_tile_swz(kbase + (size_t)((t0 + 64) & 1023) * 64, 64, Kb[cur ^ 1],
                   tid);
    // --- QK^T from Kb[cur] (landed + barrier'd at end of previous iter)
    floatx4 S[4];
#pragma unroll
    for (int j = 0; j < 4; ++j) {
      bf16x8 kf0 = read_frag_swz(Kb[cur], j * 16 + c, quad);
      bf16x8 kf1 = read_frag_swz(Kb[cur], j * 16 + c, quad + 4);
      floatx4 z = {};
      z = mfma16(kf0, qf0, z);
      S[j] = mfma16(kf1, qf1, z);
    }
    // --- relative-position bias
    const int dlt0 = qb + c - t0;
    if (t0 <= qb - 190) {
#pragma unroll
      for (int j = 0; j < 4; ++j)
#pragma unroll
        for (int r = 0; r < 4; ++r) S[j][r] += blo;
    } else if (t0 >= qb + 142) {
#pragma unroll
      for (int j = 0; j < 4; ++j)
#pragma unroll
        for (int r = 0; r < 4; ++r) S[j][r] += bhi;
    } else {
#pragma unroll
      for (int j = 0; j < 4; ++j)
#pragma unroll
        for (int r = 0; r < 4; ++r) {
          int dlt = dlt0 - j * 16 - quad * 4 - r;
          dlt = dlt > 127 ? 127 : (dlt < -127 ? -127 : dlt);
          S[j][r] += __bfloat162float(rowE[dlt + 127]);
        }
    }
    // --- online softmax
    float mx = -1e30f;
#pragma unroll
    for (int j = 0; j < 4; ++j)
#pragma unroll
      for (int r = 0; r < 4; ++r) mx = fmaxf(mx, S[j][r]);
    mx = fmaxf(mx, __shfl_xor(mx, 16, 64));
    mx = fmaxf(mx, __shfl_xor(mx, 32, 64));
    float nm = fmaxf(mrow, mx);
    float alpha = __expf(mrow - nm);
    float rs = 0.f;
#pragma unroll
    for (int j = 0; j < 4; ++j)
#pragma unroll
      for (int r = 0; r < 4; ++r) {
        float p = __expf(S[j][r] - nm);
        S[j][r] = p;
        rs += p;
      }
    rs += __shfl_xor(rs, 16, 64);
    rs += __shfl_xor(rs, 32, 64);
    lrow = lrow * alpha + rs;
    mrow = nm;
    __builtin_amdgcn_s_barrier();  // mid: all waves done reading Kb[cur]
    // --- P through wave-private stride-72 rows aliased on Kb[cur]
    bf16* rowP = Kb[cur] + (size_t)(w * 16 + c) * 72;
#pragma unroll
    for (int j = 0; j < 4; ++j) {
      alignas(8) bf16 tmp[4];
#pragma unroll
      for (int r = 0; r < 4; ++r) tmp[r] = __float2bfloat16(S[j][r]);
      *(uint64_t*)(rowP + j * 16 + quad * 4) = *(const uint64_t*)tmp;
    }
    float av[4];
#pragma unroll
    for (int r = 0; r < 4; ++r) av[r] = __shfl(alpha, quad * 4 + r, 64);
#pragma unroll
    for (int jj = 0; jj < 4; ++jj)
#pragma unroll
      for (int r = 0; r < 4; ++r) o[jj][r] *= av[r];
    __threadfence_block();
    __builtin_amdgcn_wave_barrier();
    bf16x8 pf0 = *(const bf16x8*)(rowP + quad * 8);
    bf16x8 pf1 = *(const bf16x8*)(rowP + 32 + quad * 8);
#pragma unroll
    for (int jj = 0; jj < 4; ++jj) {
      o[jj] = mfma16(pf0, vf[jj][0], o[jj]);
      o[jj] = mfma16(pf1, vf[jj][1], o[jj]);
    }
    // --- end of iter: next K tile landed (it flew across the whole compute
    // phase); all waves done with P reads -> buffer may be re-staged.
    asm volatile("s_waitcnt vmcnt(0)" ::: "memory");
    __builtin_amdgcn_s_barrier();
  }

  float lr4[4];
#pragma unroll
  for (int r = 0; r < 4; ++r) lr4[r] = __shfl(lrow, quad * 4 + r, 64);
#pragma unroll
  for (int jj = 0; jj < 4; ++jj)
#pragma unroll
    for (int r = 0; r < 4; ++r) {
      int qi = qb + quad * 4 + r;
      out[(((size_t)b * 1024 + qi) * 16 + h) * 64 + jj * 16 + c] =
          __float2bfloat16(o[jj][r] / lr4[r]);
    }
}

// ---------------------------------------------------------------------------
// Memory plan (ws stays at the PROVEN 24 MB; weights overlap dead regions):
//   d_out (32 MB fp32): [0,16M) q bf16 | [16M,32M) x_bf16 (both dead before
//     gemm_o overwrites d_out).
//   ws: k 4MB @0 | vT 4MB @4M | attn 16MB @8M
//   Wq/Wk/Wv_bf @8M/10M/10.5M  (inside attn region; dead before attn_kernel
//     writes it — stream-ordered).
//   Wo_bf @0 (inside k region; converted AFTER attn_kernel consumed k).
// ---------------------------------------------------------------------------
extern "C" void kernel_launch(void* const* d_in, const int* in_sizes, int n_in,
                              void* d_out, int out_size, void* d_ws,
                              size_t ws_size, hipStream_t stream) {
  const float* x = (const float*)d_in[0];
  const float* Wq = (const float*)d_in[1];
  const float* Wk = (const float*)d_in[2];
  const float* Wv = (const float*)d_in[3];
  const float* Wo = (const float*)d_in[4];
  const float* E = (const float*)d_in[5];

  char* ws = (char*)d_ws;
  bf16* q_ws = (bf16*)d_out;                           // [0,16M) of d_out
  bf16* x_bf = (bf16*)((char*)d_out + (16ull << 20));  // [16M,32M) of d_out
  bf16* k_ws = (bf16*)(ws);
  bf16* vT = (bf16*)(ws + (4ull << 20));
  bf16* attn = (bf16*)(ws + (8ull << 20));
  bf16* Wq_bf = (bf16*)(ws + (8ull << 20));            // 2 MB   (attn region)
  bf16* Wk_bf = (bf16*)(ws + (10ull << 20));           // 0.5 MB (attn region)
  bf16* Wv_bf = (bf16*)(ws + (10ull << 20) + (512ull << 10));  // 0.5 MB
  bf16* Wo_bf = (bf16*)(ws);                           // 2 MB   (k region)
  float* outp = (float*)d_out;

  cvt_bf16<<<2048, 256, 0, stream>>>(x, x_bf, 2097152);
  cvt_bf16<<<1024, 256, 0, stream>>>(Wq, Wq_bf, 262144);
  cvt_bf16<<<256, 256, 0, stream>>>(Wk, Wk_bf, 65536);
  cvt_bf16<<<256, 256, 0, stream>>>(Wv, Wv_bf, 65536);
  gemm_qkv<<<dim3(12, 64), 256, 0, stream>>>(x_bf, Wq_bf, Wk_bf, Wv_bf,
                                             q_ws, k_ws, vT);
  attn_kernel<<<dim3(16, 128), 256, 0, stream>>>(q_ws, k_ws, vT, E, attn);
  cvt_bf16<<<1024, 256, 0, stream>>>(Wo, Wo_bf, 262144);
  gemm_o<<<dim3(8, 64), 256, 0, stream>>>(attn, Wo_bf, outp);
}

// Round 4
// 293.857 us; speedup vs baseline: 1.5172x; 1.3410x over previous
//
#include <hip/hip_runtime.h>
#include <hip/hip_bf16.h>
#include <cstdint>
#include <cstddef>

typedef __hip_bfloat16 bf16;
typedef __attribute__((ext_vector_type(8))) __bf16 bf16x8;
typedef __attribute__((ext_vector_type(4))) float floatx4;

#define GPTR(p) ((const __attribute__((address_space(1))) void*)(p))
#define LPTR(p) ((__attribute__((address_space(3))) void*)(p))

__device__ __forceinline__ floatx4 mfma16(bf16x8 a, bf16x8 b, floatx4 c) {
  return __builtin_amdgcn_mfma_f32_16x16x32_bf16(a, b, c, 0, 0, 0);
}

// ---------------------------------------------------------------------------
// fp32 -> bf16 bulk convert
// ---------------------------------------------------------------------------
__global__ __launch_bounds__(256) void cvt_bf16(const float* __restrict__ in,
                                                bf16* __restrict__ out, int n4) {
  for (int i = blockIdx.x * 256 + threadIdx.x; i < n4; i += gridDim.x * 256) {
    float4 v = ((const float4*)in)[i];
    alignas(8) bf16 t[4] = {__float2bfloat16(v.x), __float2bfloat16(v.y),
                            __float2bfloat16(v.z), __float2bfloat16(v.w)};
    *(uint64_t*)(out + (size_t)i * 4) = *(const uint64_t*)t;
  }
}

// ---------------------------------------------------------------------------
// Fused QKV projection: A[8192,1024](bf16) @ [Wq;Wk;Wv](bf16)^T.
// m97 structure: 128x128 tile, BK=32, both sides global_load_lds width=16.
// ---------------------------------------------------------------------------
__global__ __launch_bounds__(256) void gemm_qkv(
    const bf16* __restrict__ A, const bf16* __restrict__ Wq,
    const bf16* __restrict__ Wk, const bf16* __restrict__ Wv,
    bf16* __restrict__ qout, bf16* __restrict__ kout,
    bf16* __restrict__ vTout) {
  __shared__ alignas(16) bf16 As[128 * 32];
  __shared__ alignas(16) bf16 Bs[128 * 32];
  const int tid = threadIdx.x;
  const int lane = tid & 63;
  const int w = tid >> 6;
  const int wr = w >> 1, wc = w & 1;
  const int quad = lane >> 4, c = lane & 15;
  const int m0 = blockIdx.y * 128;
  const int nb = blockIdx.x;

  int mode, nloc;
  const bf16* Wp;
  if (nb < 8) {
    mode = 1; Wp = Wq + (size_t)nb * 128 * 1024; nloc = nb * 128;
  } else if (nb < 10) {
    mode = 2; Wp = Wk + (size_t)(nb - 8) * 128 * 1024; nloc = (nb - 8) * 128;
  } else {
    mode = 3; Wp = Wv + (size_t)(nb - 10) * 128 * 1024; nloc = (nb - 10) * 128;
  }

  const int i0 = tid, i1 = tid + 256;
  const bf16* ga0 = A + (size_t)(m0 + (i0 >> 2)) * 1024 + (i0 & 3) * 8;
  const bf16* ga1 = A + (size_t)(m0 + (i1 >> 2)) * 1024 + (i1 & 3) * 8;
  const bf16* gb0 = Wp + (size_t)(i0 >> 2) * 1024 + (i0 & 3) * 8;
  const bf16* gb1 = Wp + (size_t)(i1 >> 2) * 1024 + (i1 & 3) * 8;

  floatx4 acc[4][4] = {};

  for (int kt = 0; kt < 32; ++kt) {
    if (kt) __syncthreads();
    __builtin_amdgcn_global_load_lds(GPTR(ga0), LPTR(&As[i0 * 8]), 16, 0, 0);
    __builtin_amdgcn_global_load_lds(GPTR(ga1), LPTR(&As[i1 * 8]), 16, 0, 0);
    __builtin_amdgcn_global_load_lds(GPTR(gb0), LPTR(&Bs[i0 * 8]), 16, 0, 0);
    __builtin_amdgcn_global_load_lds(GPTR(gb1), LPTR(&Bs[i1 * 8]), 16, 0, 0);
    ga0 += 32; ga1 += 32; gb0 += 32; gb1 += 32;
    __syncthreads();
    bf16x8 af[4], bfr[4];
#pragma unroll
    for (int i = 0; i < 4; ++i)
      af[i] = *(const bf16x8*)&As[(wr * 64 + i * 16 + c) * 32 + quad * 8];
#pragma unroll
    for (int j = 0; j < 4; ++j)
      bfr[j] = *(const bf16x8*)&Bs[(wc * 64 + j * 16 + c) * 32 + quad * 8];
#pragma unroll
    for (int i = 0; i < 4; ++i)
#pragma unroll
      for (int j = 0; j < 4; ++j)
        acc[i][j] = mfma16(af[i], bfr[j], acc[i][j]);
  }

  if (mode == 3) {  // vT[((b*4+g)*64+d)*1024+t]: 4 consecutive t -> 8B store
#pragma unroll
    for (int i = 0; i < 4; ++i)
#pragma unroll
      for (int j = 0; j < 4; ++j) {
        int m = m0 + wr * 64 + i * 16 + quad * 4;
        int n = nloc + wc * 64 + j * 16 + c;
        int b = m >> 10, t = m & 1023, g = n >> 6, d = n & 63;
        alignas(8) bf16 tmp[4];
#pragma unroll
        for (int r = 0; r < 4; ++r) tmp[r] = __float2bfloat16(acc[i][j][r]);
        *(uint64_t*)(vTout + (((size_t)(b * 4 + g)) * 64 + d) * 1024 + t) =
            *(const uint64_t*)tmp;
      }
    return;
  }

  const float scale = (mode == 1) ? 0.125f : 1.0f;
#pragma unroll
  for (int i = 0; i < 4; ++i)
#pragma unroll
    for (int j = 0; j < 4; ++j)
#pragma unroll
      for (int r = 0; r < 4; ++r) {
        int m = m0 + wr * 64 + i * 16 + quad * 4 + r;
        int n = nloc + wc * 64 + j * 16 + c;
        int b = m >> 10, t = m & 1023;
        bf16 v = __float2bfloat16(acc[i][j][r] * scale);
        if (mode == 1) {
          int h = n >> 6;
          qout[(((size_t)(b * 16 + h)) * 1024 + t) * 64 + (n & 63)] = v;
        } else {
          int g = n >> 6;
          kout[(((size_t)(b * 4 + g)) * 1024 + t) * 64 + (n & 63)] = v;
        }
      }
}

// ---------------------------------------------------------------------------
// O-projection: attn[8192,1024](bf16) @ Wo(bf16)^T -> fp32 d_out.
// ---------------------------------------------------------------------------
__global__ __launch_bounds__(256) void gemm_o(const bf16* __restrict__ A,
                                              const bf16* __restrict__ W,
                                              float* __restrict__ out) {
  __shared__ alignas(16) bf16 As[128 * 32];
  __shared__ alignas(16) bf16 Bs[128 * 32];
  const int tid = threadIdx.x;
  const int lane = tid & 63;
  const int w = tid >> 6;
  const int wr = w >> 1, wc = w & 1;
  const int quad = lane >> 4, c = lane & 15;
  const int m0 = blockIdx.y * 128, n0 = blockIdx.x * 128;

  const int i0 = tid, i1 = tid + 256;
  const bf16* ga0 = A + (size_t)(m0 + (i0 >> 2)) * 1024 + (i0 & 3) * 8;
  const bf16* ga1 = A + (size_t)(m0 + (i1 >> 2)) * 1024 + (i1 & 3) * 8;
  const bf16* gb0 = W + (size_t)(n0 + (i0 >> 2)) * 1024 + (i0 & 3) * 8;
  const bf16* gb1 = W + (size_t)(n0 + (i1 >> 2)) * 1024 + (i1 & 3) * 8;

  floatx4 acc[4][4] = {};

  for (int kt = 0; kt < 32; ++kt) {
    if (kt) __syncthreads();
    __builtin_amdgcn_global_load_lds(GPTR(ga0), LPTR(&As[i0 * 8]), 16, 0, 0);
    __builtin_amdgcn_global_load_lds(GPTR(ga1), LPTR(&As[i1 * 8]), 16, 0, 0);
    __builtin_amdgcn_global_load_lds(GPTR(gb0), LPTR(&Bs[i0 * 8]), 16, 0, 0);
    __builtin_amdgcn_global_load_lds(GPTR(gb1), LPTR(&Bs[i1 * 8]), 16, 0, 0);
    ga0 += 32; ga1 += 32; gb0 += 32; gb1 += 32;
    __syncthreads();
    bf16x8 af[4], bfr[4];
#pragma unroll
    for (int i = 0; i < 4; ++i)
      af[i] = *(const bf16x8*)&As[(wr * 64 + i * 16 + c) * 32 + quad * 8];
#pragma unroll
    for (int j = 0; j < 4; ++j)
      bfr[j] = *(const bf16x8*)&Bs[(wc * 64 + j * 16 + c) * 32 + quad * 8];
#pragma unroll
    for (int i = 0; i < 4; ++i)
#pragma unroll
      for (int j = 0; j < 4; ++j)
        acc[i][j] = mfma16(af[i], bfr[j], acc[i][j]);
  }

#pragma unroll
  for (int i = 0; i < 4; ++i)
#pragma unroll
    for (int j = 0; j < 4; ++j)
#pragma unroll
      for (int r = 0; r < 4; ++r) {
        int m = m0 + wr * 64 + i * 16 + quad * 4 + r;
        int n = n0 + wc * 64 + j * 16 + c;
        out[(size_t)m * 1024 + n] = acc[i][j][r];
      }
}

// ---------------------------------------------------------------------------
// Staged 64x64 bf16 tile with XOR-8 column-block swizzle (verified r0).
// ---------------------------------------------------------------------------
__device__ __forceinline__ void stage_tile_swz(const bf16* __restrict__ g,
                                               int gstride, bf16* __restrict__ dst,
                                               int tid) {
#pragma unroll
  for (int s = 0; s < 2; ++s) {
    int f = s * 256 + tid;
    int r = f >> 3, cb = f & 7;
    int cbg = cb ^ (r & 7);
    __builtin_amdgcn_global_load_lds(GPTR(g + (size_t)r * gstride + cbg * 8),
                                     LPTR(dst + f * 8), 16, 0, 0);
  }
}

__device__ __forceinline__ bf16x8 read_frag_swz(const bf16* __restrict__ tile,
                                                int row, int cb) {
  return *(const bf16x8*)&tile[row * 64 + ((cb ^ (row & 7)) * 8)];
}

// ---------------------------------------------------------------------------
// Flash attention, S^T = K.Q^T form.  Round-4.
// r3 post-mortem: counted vmcnt(2) mid-wait raced (global_load_lds retire
// order vs LDS-write visibility not guaranteed oldest-first) -> flaky
// post-timing divergence.  RULE: only vmcnt(0) waits with global_load_lds.
// Pipeline depth now comes from buffer count: BOTH K and V double-buffered,
// prefetched one FULL tile ahead.
//   per tile: issue V[t+1]->nxtV, K[t+1]->nxtK at top; QK+bias+softmax on
//   curK; bare s_barrier (mid; curK reads complete by data-dep before
//   arrival; sched_barrier(0) fences stop reads sinking across); P aliases
//   curK; PV from curV (landed at previous tile's end); ONE vmcnt(0) +
//   s_barrier at END -- prefetches had a whole tile of compute to fly.
// All buffers statically distinct (Ka/Kc/Va/Vc, unroll x2) -> no may-alias
// drains (r2 lesson).
// LDS: qEl 33792 + 2*9216 + 2*8192 = 68608 -> 2 blocks/CU.
// ---------------------------------------------------------------------------
__device__ __forceinline__ void attn_tile(
    int t0, const bf16* __restrict__ kbase, const bf16* __restrict__ vbase,
    bf16* __restrict__ curK, bf16* __restrict__ nxtK,
    bf16* __restrict__ curV, bf16* __restrict__ nxtV,
    const bf16* __restrict__ rowE, int qb, int tid, int w, int quad, int c,
    bf16x8 qf0, bf16x8 qf1, float blo, float bhi, float& mrow, float& lrow,
    floatx4 (&o)[4]) {
  // --- prefetch NEXT tile's V and K (consumed next iter; drained at END)
  const int nt0 = (t0 + 64) & 1023;
  stage_tile_swz(vbase + nt0, 1024, nxtV, tid);
  stage_tile_swz(kbase + (size_t)nt0 * 64, 64, nxtK, tid);
  // --- QK^T from curK (landed + barrier'd at end of previous tile)
  floatx4 S[4];
#pragma unroll
  for (int j = 0; j < 4; ++j) {
    bf16x8 kf0 = read_frag_swz(curK, j * 16 + c, quad);
    bf16x8 kf1 = read_frag_swz(curK, j * 16 + c, quad + 4);
    floatx4 z = {};
    z = mfma16(kf0, qf0, z);
    S[j] = mfma16(kf1, qf1, z);
  }
  // --- relative-position bias
  const int dlt0 = qb + c - t0;
  if (t0 <= qb - 190) {
#pragma unroll
    for (int j = 0; j < 4; ++j)
#pragma unroll
      for (int r = 0; r < 4; ++r) S[j][r] += blo;
  } else if (t0 >= qb + 142) {
#pragma unroll
    for (int j = 0; j < 4; ++j)
#pragma unroll
      for (int r = 0; r < 4; ++r) S[j][r] += bhi;
  } else {
#pragma unroll
    for (int j = 0; j < 4; ++j)
#pragma unroll
      for (int r = 0; r < 4; ++r) {
        int dlt = dlt0 - j * 16 - quad * 4 - r;
        dlt = dlt > 127 ? 127 : (dlt < -127 ? -127 : dlt);
        S[j][r] += __bfloat162float(rowE[dlt + 127]);
      }
  }
  // --- online softmax
  float mx = -1e30f;
#pragma unroll
  for (int j = 0; j < 4; ++j)
#pragma unroll
    for (int r = 0; r < 4; ++r) mx = fmaxf(mx, S[j][r]);
  mx = fmaxf(mx, __shfl_xor(mx, 16, 64));
  mx = fmaxf(mx, __shfl_xor(mx, 32, 64));
  float nm = fmaxf(mrow, mx);
  float alpha = __expf(mrow - nm);
  float rs = 0.f;
#pragma unroll
  for (int j = 0; j < 4; ++j)
#pragma unroll
    for (int r = 0; r < 4; ++r) {
      float p = __expf(S[j][r] - nm);
      S[j][r] = p;
      rs += p;
    }
  rs += __shfl_xor(rs, 16, 64);
  rs += __shfl_xor(rs, 32, 64);
  lrow = lrow * alpha + rs;
  mrow = nm;
  // --- mid barrier: all waves arrived => all curK ds_reads complete
  // (data-dep before their MFMAs).  sched_barrier fences stop the compiler
  // sinking curK reads below / hoisting P writes above.
  __builtin_amdgcn_sched_barrier(0);
  __builtin_amdgcn_s_barrier();
  __builtin_amdgcn_sched_barrier(0);
  // --- P through wave-private stride-72 rows aliased on curK
  bf16* rowP = curK + (size_t)(w * 16 + c) * 72;
#pragma unroll
  for (int j = 0; j < 4; ++j) {
    alignas(8) bf16 tmp[4];
#pragma unroll
    for (int r = 0; r < 4; ++r) tmp[r] = __float2bfloat16(S[j][r]);
    *(uint64_t*)(rowP + j * 16 + quad * 4) = *(const uint64_t*)tmp;
  }
  float av[4];
#pragma unroll
  for (int r = 0; r < 4; ++r) av[r] = __shfl(alpha, quad * 4 + r, 64);
#pragma unroll
  for (int jj = 0; jj < 4; ++jj)
#pragma unroll
    for (int r = 0; r < 4; ++r) o[jj][r] *= av[r];
  __threadfence_block();
  __builtin_amdgcn_wave_barrier();
  bf16x8 pf0 = *(const bf16x8*)(rowP + quad * 8);
  bf16x8 pf1 = *(const bf16x8*)(rowP + 32 + quad * 8);
#pragma unroll
  for (int jj = 0; jj < 4; ++jj) {
    bf16x8 vf0 = read_frag_swz(curV, jj * 16 + c, quad);
    bf16x8 vf1 = read_frag_swz(curV, jj * 16 + c, quad + 4);
    o[jj] = mfma16(pf0, vf0, o[jj]);
    o[jj] = mfma16(pf1, vf1, o[jj]);
  }
  // --- end: prefetched K[t+1]/V[t+1] landed (flew across whole tile);
  // all waves done with P/curV -> next tile may consume/restage.
  asm volatile("s_waitcnt vmcnt(0)" ::: "memory");
  __builtin_amdgcn_sched_barrier(0);
  __builtin_amdgcn_s_barrier();
  __builtin_amdgcn_sched_barrier(0);
}

__global__ __launch_bounds__(256, 2) void attn_kernel(
    const bf16* __restrict__ q_ws, const bf16* __restrict__ k_ws,
    const bf16* __restrict__ vT, const float* __restrict__ E,
    bf16* __restrict__ out) {
  __shared__ alignas(16) bf16 qEl[64 * 264];  // bias table, rows lane-private
  __shared__ alignas(16) bf16 Ka[64 * 72];    // K buf A / P rows
  __shared__ alignas(16) bf16 Kc[64 * 72];    // K buf B / P rows
  __shared__ alignas(16) bf16 Va[64 * 64];    // V^T buf A
  __shared__ alignas(16) bf16 Vc[64 * 64];    // V^T buf B
  const int tid = threadIdx.x;
  const int lane = tid & 63, w = tid >> 6;
  const int quad = lane >> 4, c = lane & 15;
  const int bh = blockIdx.y;
  const int b = bh >> 4, h = bh & 15, g = h >> 2;
  const int qb = blockIdx.x * 64 + w * 16;

  const bf16* kbase = k_ws + (size_t)(b * 4 + g) * 1024 * 64;
  const bf16* vbase = vT + (size_t)(b * 4 + g) * 64 * 1024;

  // Tile-0 K and V prefetch hide under the qE preamble; the preamble's
  // __syncthreads (full drain) lands them for all waves.
  stage_tile_swz(kbase, 64, Ka, tid);
  stage_tile_swz(vbase, 1024, Va, tid);

  const bf16* qrow = q_ws + ((size_t)bh * 1024 + qb + c) * 64;
  bf16x8 qf0 = *(const bf16x8*)(qrow + quad * 8);
  bf16x8 qf1 = *(const bf16x8*)(qrow + 32 + quad * 8);

  // qE[qlocal][p] = q.E[p]  (wave's rows w*16..w*16+15; p in [0,254])
  for (int jn = 0; jn < 16; ++jn) {
    int er = jn * 16 + c;
    er = er > 254 ? 254 : er;
    const float* Ep = E + (size_t)er * 64;
    float4 e0 = *(const float4*)(Ep + quad * 8);
    float4 e1 = *(const float4*)(Ep + quad * 8 + 4);
    float4 e2 = *(const float4*)(Ep + 32 + quad * 8);
    float4 e3 = *(const float4*)(Ep + 32 + quad * 8 + 4);
    alignas(16) bf16 t0b[8] = {
        __float2bfloat16(e0.x), __float2bfloat16(e0.y), __float2bfloat16(e0.z),
        __float2bfloat16(e0.w), __float2bfloat16(e1.x), __float2bfloat16(e1.y),
        __float2bfloat16(e1.z), __float2bfloat16(e1.w)};
    alignas(16) bf16 t1b[8] = {
        __float2bfloat16(e2.x), __float2bfloat16(e2.y), __float2bfloat16(e2.z),
        __float2bfloat16(e2.w), __float2bfloat16(e3.x), __float2bfloat16(e3.y),
        __float2bfloat16(e3.z), __float2bfloat16(e3.w)};
    floatx4 a = {};
    a = mfma16(qf0, *(const bf16x8*)t0b, a);
    a = mfma16(qf1, *(const bf16x8*)t1b, a);
#pragma unroll
    for (int r = 0; r < 4; ++r)
      qEl[(w * 16 + quad * 4 + r) * 264 + jn * 16 + c] = __float2bfloat16(a[r]);
  }
  __syncthreads();  // qEl ready + K0/V0 landed (single full drain)

  const bf16* rowE = qEl + (size_t)(w * 16 + c) * 264;
  float mrow = -1e30f, lrow = 0.f;
  floatx4 o[4] = {};
  const float blo = __bfloat162float(rowE[254]);
  const float bhi = __bfloat162float(rowE[0]);

  // 16 tiles, unrolled x2 so all buffer choices are compile-time static.
#pragma unroll 1
  for (int tp = 0; tp < 8; ++tp) {
    attn_tile(tp * 128, kbase, vbase, Ka, Kc, Va, Vc, rowE, qb, tid, w, quad,
              c, qf0, qf1, blo, bhi, mrow, lrow, o);
    attn_tile(tp * 128 + 64, kbase, vbase, Kc, Ka, Vc, Va, rowE, qb, tid, w,
              quad, c, qf0, qf1, blo, bhi, mrow, lrow, o);
  }

  float lr4[4];
#pragma unroll
  for (int r = 0; r < 4; ++r) lr4[r] = __shfl(lrow, quad * 4 + r, 64);
#pragma unroll
  for (int jj = 0; jj < 4; ++jj)
#pragma unroll
    for (int r = 0; r < 4; ++r) {
      int qi = qb + quad * 4 + r;
      out[(((size_t)b * 1024 + qi) * 16 + h) * 64 + jj * 16 + c] =
          __float2bfloat16(o[jj][r] / lr4[r]);
    }
}

// ---------------------------------------------------------------------------
// Memory plan (unchanged, proven):
//   d_out (32 MB fp32): [0,16M) q bf16 | [16M,32M) x_bf16.
//   ws: k 4MB @0 | vT 4MB @4M | attn 16MB @8M
//   Wq/Wk/Wv_bf @8M/10M/10.5M (attn region, dead before attn_kernel writes).
//   Wo_bf @0 (k region; converted AFTER attn_kernel consumed k).
// ---------------------------------------------------------------------------
extern "C" void kernel_launch(void* const* d_in, const int* in_sizes, int n_in,
                              void* d_out, int out_size, void* d_ws,
                              size_t ws_size, hipStream_t stream) {
  const float* x = (const float*)d_in[0];
  const float* Wq = (const float*)d_in[1];
  const float* Wk = (const float*)d_in[2];
  const float* Wv = (const float*)d_in[3];
  const float* Wo = (const float*)d_in[4];
  const float* E = (const float*)d_in[5];

  char* ws = (char*)d_ws;
  bf16* q_ws = (bf16*)d_out;                           // [0,16M) of d_out
  bf16* x_bf = (bf16*)((char*)d_out + (16ull << 20));  // [16M,32M) of d_out
  bf16* k_ws = (bf16*)(ws);
  bf16* vT = (bf16*)(ws + (4ull << 20));
  bf16* attn = (bf16*)(ws + (8ull << 20));
  bf16* Wq_bf = (bf16*)(ws + (8ull << 20));            // 2 MB   (attn region)
  bf16* Wk_bf = (bf16*)(ws + (10ull << 20));           // 0.5 MB (attn region)
  bf16* Wv_bf = (bf16*)(ws + (10ull << 20) + (512ull << 10));  // 0.5 MB
  bf16* Wo_bf = (bf16*)(ws);                           // 2 MB   (k region)
  float* outp = (float*)d_out;

  cvt_bf16<<<2048, 256, 0, stream>>>(x, x_bf, 2097152);
  cvt_bf16<<<1024, 256, 0, stream>>>(Wq, Wq_bf, 262144);
  cvt_bf16<<<256, 256, 0, stream>>>(Wk, Wk_bf, 65536);
  cvt_bf16<<<256, 256, 0, stream>>>(Wv, Wv_bf, 65536);
  gemm_qkv<<<dim3(12, 64), 256, 0, stream>>>(x_bf, Wq_bf, Wk_bf, Wv_bf,
                                             q_ws, k_ws, vT);
  attn_kernel<<<dim3(16, 128), 256, 0, stream>>>(q_ws, k_ws, vT, E, attn);
  cvt_bf16<<<1024, 256, 0, stream>>>(Wo, Wo_bf, 262144);
  gemm_o<<<dim3(8, 64), 256, 0, stream>>>(attn, Wo_bf, outp);
}